// Round 1
// baseline (9492.628 us; speedup 1.0000x reference)
//
#include <hip/hip_runtime.h>
#include <hip/hip_bf16.h>

// Problem constants
#define BNW   4096           // windows
#define L     49             // tokens per window
#define C     512            // channels
#define NH    16             // heads
#define HD    32             // head dim
#define M_TOT (BNW * L)      // 200704 rows
#define N_QKV (3 * C)        // 1536
#define CH_STRIDE ((size_t)M_TOT)  // qkvT row stride (per channel)

// ---------------------------------------------------------------------------
// Kernel 1: qkvT[ch][m] = sum_k x[m][k] * w_qkv[k][ch] + b_qkv[ch]
// 64x64 tile, 256 threads, 4x4 per thread. Output transposed, coalesced in m.
// ---------------------------------------------------------------------------
__global__ __launch_bounds__(256) void qkv_gemm_t(
    const float* __restrict__ x, const float* __restrict__ w,
    const float* __restrict__ bias, float* __restrict__ outT) {
  __shared__ float xs[16][65];  // [k][m]
  __shared__ float ws[16][65];  // [k][n]
  const int m0 = blockIdx.x * 64;
  const int n0 = blockIdx.y * 64;
  const int t  = threadIdx.x;
  const int tx = t & 15;   // m-group
  const int ty = t >> 4;   // n-group
  float acc[4][4];         // [j(n)][i(m)]
#pragma unroll
  for (int j = 0; j < 4; ++j)
#pragma unroll
    for (int i = 0; i < 4; ++i) acc[j][i] = 0.f;

  for (int k0 = 0; k0 < 512; k0 += 16) {
    {
      const int r  = t >> 2;         // 0..63 (m row)
      const int kq = (t & 3) * 4;    // k sub
      const float4 xv = *(const float4*)(x + (size_t)(m0 + r) * 512 + k0 + kq);
      xs[kq + 0][r] = xv.x; xs[kq + 1][r] = xv.y;
      xs[kq + 2][r] = xv.z; xs[kq + 3][r] = xv.w;
    }
    {
      const int kk = t >> 4;         // 0..15
      const int j  = (t & 15) * 4;
      const float4 wv = *(const float4*)(w + (size_t)(k0 + kk) * 1536 + n0 + j);
      ws[kk][j + 0] = wv.x; ws[kk][j + 1] = wv.y;
      ws[kk][j + 2] = wv.z; ws[kk][j + 3] = wv.w;
    }
    __syncthreads();
#pragma unroll
    for (int kk = 0; kk < 16; ++kk) {
      float a[4], b[4];
#pragma unroll
      for (int i = 0; i < 4; ++i) a[i] = xs[kk][tx * 4 + i];
#pragma unroll
      for (int j = 0; j < 4; ++j) b[j] = ws[kk][ty * 4 + j];
#pragma unroll
      for (int j = 0; j < 4; ++j)
#pragma unroll
        for (int i = 0; i < 4; ++i) acc[j][i] += a[i] * b[j];
    }
    __syncthreads();
  }
#pragma unroll
  for (int j = 0; j < 4; ++j) {
    const int n = n0 + ty * 4 + j;
    const float bn = bias[n];
    float4 o;
    o.x = acc[j][0] + bn; o.y = acc[j][1] + bn;
    o.z = acc[j][2] + bn; o.w = acc[j][3] + bn;
    *(float4*)(outT + (size_t)n * CH_STRIDE + m0 + tx * 4) = o;
  }
}

// ---------------------------------------------------------------------------
// Kernel 2: per-(window, head) attention. One block (64 threads = 1 wave) per
// (b,h). Thread t<49 owns query row t: q-row + logits row in registers, k/v in
// LDS (reads are wave-broadcast, conflict-free). Writes y in (B, L, C) layout.
// ---------------------------------------------------------------------------
__global__ __launch_bounds__(64) void attn_win(
    const float* __restrict__ qkvT, const float* __restrict__ mask,
    const float* __restrict__ bias_table, const int* __restrict__ index_table,
    float* __restrict__ y) {
  __shared__ float k_s[L * HD];  // 1568
  __shared__ float v_s[L * HD];  // 1568
  const int bh = blockIdx.x;
  const int b = bh >> 4;
  const int h = bh & 15;
  // contiguous q/k/v chunks thanks to the transposed qkv layout
  const size_t base = (size_t)(b >> 3) * CH_STRIDE +
                      (size_t)((b & 7) * 512 + h * 32) * 49;
  const float* uq = qkvT + base;
  const float* uk = uq + (size_t)512 * CH_STRIDE;
  const float* uv = uq + (size_t)1024 * CH_STRIDE;
  const int t = threadIdx.x;

  for (int i = t; i < (L * HD) / 4; i += 64) {  // 392 float4 each
    ((float4*)k_s)[i] = ((const float4*)uk)[i];
    ((float4*)v_s)[i] = ((const float4*)uv)[i];
  }

  float qr[HD];
  if (t < L) {
#pragma unroll
    for (int i = 0; i < 8; ++i) {
      const float4 qv = ((const float4*)(uq + t * HD))[i];
      qr[i * 4 + 0] = qv.x; qr[i * 4 + 1] = qv.y;
      qr[i * 4 + 2] = qv.z; qr[i * 4 + 3] = qv.w;
    }
  }
  __syncthreads();

  if (t < L) {
    const float* mrow = mask + (size_t)(b & 63) * (L * L) + t * L;
    const int*   irow = index_table + t * L;
    float s[L];
#pragma unroll
    for (int m = 0; m < L; ++m) {
      float acc = 0.f;
#pragma unroll
      for (int d = 0; d < HD; ++d) acc += qr[d] * k_s[m * HD + d];
      s[m] = acc + bias_table[irow[m] * NH + h] + mrow[m];
    }
    float mx = s[0];
#pragma unroll
    for (int m = 1; m < L; ++m) mx = fmaxf(mx, s[m]);
    float sum = 0.f;
#pragma unroll
    for (int m = 0; m < L; ++m) { s[m] = __expf(s[m] - mx); sum += s[m]; }
    const float inv = 1.f / sum;
    float o[HD];
#pragma unroll
    for (int d = 0; d < HD; ++d) o[d] = 0.f;
#pragma unroll
    for (int m = 0; m < L; ++m) {
      const float p = s[m] * inv;
#pragma unroll
      for (int d = 0; d < HD; ++d) o[d] += p * v_s[m * HD + d];
    }
    float* yp = y + (size_t)b * (L * C) + (size_t)t * C + h * HD;
#pragma unroll
    for (int d = 0; d < 8; ++d) {
      float4 ov;
      ov.x = o[d * 4 + 0]; ov.y = o[d * 4 + 1];
      ov.z = o[d * 4 + 2]; ov.w = o[d * 4 + 3];
      ((float4*)yp)[d] = ov;
    }
  }
}

// ---------------------------------------------------------------------------
// Kernel 3: out[m][n] = sum_k y[m][k] * w_proj[k][n] + b_proj[n]
// ---------------------------------------------------------------------------
__global__ __launch_bounds__(256) void proj_gemm(
    const float* __restrict__ y, const float* __restrict__ w,
    const float* __restrict__ bias, float* __restrict__ out) {
  __shared__ float ys[16][65];  // [k][m]
  __shared__ float ws[16][65];  // [k][n]
  const int m0 = blockIdx.x * 64;
  const int n0 = blockIdx.y * 64;
  const int t  = threadIdx.x;
  const int tx = t & 15;   // n-group
  const int ty = t >> 4;   // m-group
  float acc[4][4];         // [i(m)][j(n)]
#pragma unroll
  for (int i = 0; i < 4; ++i)
#pragma unroll
    for (int j = 0; j < 4; ++j) acc[i][j] = 0.f;

  for (int k0 = 0; k0 < 512; k0 += 16) {
    {
      const int r  = t >> 2;
      const int kq = (t & 3) * 4;
      const float4 yv = *(const float4*)(y + (size_t)(m0 + r) * 512 + k0 + kq);
      ys[kq + 0][r] = yv.x; ys[kq + 1][r] = yv.y;
      ys[kq + 2][r] = yv.z; ys[kq + 3][r] = yv.w;
    }
    {
      const int kk = t >> 4;
      const int j  = (t & 15) * 4;
      const float4 wv = *(const float4*)(w + (size_t)(k0 + kk) * 512 + n0 + j);
      ws[kk][j + 0] = wv.x; ws[kk][j + 1] = wv.y;
      ws[kk][j + 2] = wv.z; ws[kk][j + 3] = wv.w;
    }
    __syncthreads();
#pragma unroll
    for (int kk = 0; kk < 16; ++kk) {
      float a[4], b[4];
#pragma unroll
      for (int i = 0; i < 4; ++i) a[i] = ys[kk][ty * 4 + i];
#pragma unroll
      for (int j = 0; j < 4; ++j) b[j] = ws[kk][tx * 4 + j];
#pragma unroll
      for (int i = 0; i < 4; ++i)
#pragma unroll
        for (int j = 0; j < 4; ++j) acc[i][j] += a[i] * b[j];
    }
    __syncthreads();
  }
#pragma unroll
  for (int i = 0; i < 4; ++i) {
    const int m = m0 + ty * 4 + i;
    float4 o;
    o.x = acc[i][0] + bias[n0 + tx * 4 + 0];
    o.y = acc[i][1] + bias[n0 + tx * 4 + 1];
    o.z = acc[i][2] + bias[n0 + tx * 4 + 2];
    o.w = acc[i][3] + bias[n0 + tx * 4 + 3];
    *(float4*)(out + (size_t)m * 512 + n0 + tx * 4) = o;
  }
}

// ---------------------------------------------------------------------------
extern "C" void kernel_launch(void* const* d_in, const int* in_sizes, int n_in,
                              void* d_out, int out_size, void* d_ws, size_t ws_size,
                              hipStream_t stream) {
  const float* x          = (const float*)d_in[0];
  const float* mask       = (const float*)d_in[1];
  const float* w_qkv      = (const float*)d_in[2];
  const float* b_qkv      = (const float*)d_in[3];
  const float* w_proj     = (const float*)d_in[4];
  const float* b_proj     = (const float*)d_in[5];
  const float* bias_table = (const float*)d_in[6];
  const int*   index_tab  = (const int*)d_in[7];
  float* out = (float*)d_out;

  // workspace layout: qkvT (1536 x 200704 fp32, 1.233 GB) | y (200704 x 512 fp32, 411 MB)
  float* qkvT = (float*)d_ws;
  float* y    = qkvT + (size_t)N_QKV * M_TOT;

  qkv_gemm_t<<<dim3(M_TOT / 64, N_QKV / 64), 256, 0, stream>>>(x, w_qkv, b_qkv, qkvT);
  attn_win<<<BNW * NH, 64, 0, stream>>>(qkvT, mask, bias_table, index_tab, y);
  proj_gemm<<<dim3(M_TOT / 64, C / 64), 256, 0, stream>>>(y, w_proj, b_proj, out);
}